// Round 3
// baseline (39.673 us; speedup 1.0000x reference)
//
#include <hip/hip_runtime.h>

// out[b,o] = sum_{i,n} (Ps*tanh(k*(x + Ec*bm)) + bias) * coef
// bm = 1 - 0.4*(1 - sigmoid(10*(x_b - x_{b-1}))) * sigmoid(10*(-x - Ec))
// (switch_up cancels: target = 1 - 2*switch_lo)
// tanh(a) = 1 - 2/(exp(2a)+1) -> out = base[o] - 2 * sum pc*r
//
// R3: R2 was LDS-pipe-bound (24 B/term: b128 param + b64 xc reads ~= 18-36
// cyc/wave-term, 15-30us/CU -- matches 28us measured; occupancy change was
// neutral). Restructure: thread owns (i0, n), params live in 16 VGPRs,
// loops over b. Main-loop LDS = one broadcast b64 per (slot,b) = 2 B/term.
// New floor = trans pipe: 4 trans/term -> ~7us.

#define GATE_C 14.426950408889634f   // 10*log2(e)
#define TANH_C 2.8853900817779268f   // 2*log2(e)

constexpr int B = 512, I = 128, O = 64, NB = 8, BT = 16, NS = 4;

__global__ __launch_bounds__(256, 4) void fe_main(
    const float* __restrict__ x, const float* __restrict__ k,
    const float* __restrict__ Ec, const float* __restrict__ Ps,
    const float* __restrict__ bias, const float* __restrict__ coef,
    float* __restrict__ out)
{
  __shared__ float2 xc[BT][I];        // {x, c} per (b_local, i) — 16 KB
  __shared__ float racc[BT][33];      // n-reduced partials per (b, i0); +1 pad
  __shared__ float red[4];

  const int tid = threadIdx.x;
  const int o  = blockIdx.y;
  const int b0 = blockIdx.x * BT;
  const int n  = tid & 7;             // branch index
  const int i0 = tid >> 3;            // 0..31, slot s covers i = i0 + 32*s

  // ---- params for this thread's 4 (i, n) slots -> registers ----
  float ec[NS], eg[NS], k2[NS], pc[NS];
  float pbase = 0.f;
  #pragma unroll
  for (int s = 0; s < NS; ++s) {
    const int g = ((i0 + 32 * s) * O + o) * NB + n;
    const float E = Ec[g], K = k[g], P = Ps[g], C = coef[g], Bs = bias[g];
    ec[s] = E;
    eg[s] = E * GATE_C;
    k2[s] = K * TANH_C;
    pc[s] = P * C;
    pbase += fmaf(Bs, C, pc[s]);      // base[o] partial: (Ps + bias)*coef
  }

  // ---- stage {x, c} for this batch tile (coalesced) ----
  for (int e = tid; e < BT * I; e += 256) {
    const int bl = e >> 7, i = e & 127;
    const int bg = b0 + bl;
    const float xv = x[bg * I + i];
    const float pv = (bg == 0) ? 0.f : x[(bg - 1) * I + i];
    // c = -0.4 * sigmoid(-10*(x - prev))
    const float c = -0.4f * __builtin_amdgcn_rcpf(
        1.f + __builtin_amdgcn_exp2f(GATE_C * (xv - pv)));
    xc[bl][i] = make_float2(xv, c);
  }

  // base[o]: full-wave butterfly, one partial per wave
  #pragma unroll
  for (int m = 1; m < 64; m <<= 1) pbase += __shfl_xor(pbase, m);
  if ((tid & 63) == 0) red[tid >> 6] = pbase;
  __syncthreads();

  // ---- main loop: fixed (i0,n), iterate over b; params stay in VGPRs ----
  float acc[BT];
  #pragma unroll
  for (int bl = 0; bl < BT; ++bl) acc[bl] = 0.f;

  #pragma unroll
  for (int bl = 0; bl < BT; ++bl) {
    #pragma unroll
    for (int s = 0; s < NS; ++s) {
      const float2 v = xc[bl][i0 + 32 * s];   // 8 unique addrs/wave, broadcast x8
      // crossed_neg = rcp(1 + exp2(GATE_C*x + GATE_C*Ec))
      const float sg = __builtin_amdgcn_rcpf(
          1.f + __builtin_amdgcn_exp2f(fmaf(v.x, GATE_C, eg[s])));
      const float bm    = fmaf(v.y, sg, 1.f);       // 1 + c*sg
      const float inner = fmaf(ec[s], bm, v.x);     // x + Ec*bm
      const float r = __builtin_amdgcn_rcpf(
          1.f + __builtin_amdgcn_exp2f(k2[s] * inner));
      acc[bl] = fmaf(pc[s], r, acc[bl]);
    }
  }

  // ---- reduce over n (DPP shfl, dist 1/2/4), stash per (b, i0) ----
  #pragma unroll
  for (int bl = 0; bl < BT; ++bl) {
    float a = acc[bl];
    a += __shfl_xor(a, 1);
    a += __shfl_xor(a, 2);
    a += __shfl_xor(a, 4);
    if (n == 0) racc[bl][i0] = a;
  }
  __syncthreads();

  // ---- final: thread (b = tid>>4, q = tid&15) sums 32 i0-partials ----
  const int b = tid >> 4, q = tid & 15;
  float a = racc[b][q] + racc[b][q + 16];
  a += __shfl_xor(a, 1);
  a += __shfl_xor(a, 2);
  a += __shfl_xor(a, 4);
  a += __shfl_xor(a, 8);
  if (q == 0) {
    const float base = red[0] + red[1] + red[2] + red[3];
    out[(b0 + b) * O + o] = fmaf(-2.f, a, base);
  }
}

extern "C" void kernel_launch(void* const* d_in, const int* in_sizes, int n_in,
                              void* d_out, int out_size, void* d_ws, size_t ws_size,
                              hipStream_t stream) {
  const float* x    = (const float*)d_in[0];
  const float* k    = (const float*)d_in[1];
  const float* Ec   = (const float*)d_in[2];
  const float* Ps   = (const float*)d_in[3];
  const float* bias = (const float*)d_in[4];
  const float* coef = (const float*)d_in[5];
  float* out = (float*)d_out;

  dim3 grid(B / BT, O);   // 32 batch tiles x 64 output channels
  fe_main<<<grid, 256, 0, stream>>>(x, k, Ec, Ps, bias, coef, out);
}

// Round 4
// 28.234 us; speedup vs baseline: 1.4051x; 1.4051x over previous
//
#include <hip/hip_runtime.h>

// out[b,o] = sum_{i,n} (Ps*tanh(k*(x + Ec*bm)) + bias) * coef
// bm = 1 - 0.4*(1 - sigmoid(10*(x_b - x_{b-1}))) * sigmoid(10*(-x - Ec))
// (switch_up cancels: target = 1 - 2*switch_lo)
// tanh(a) = 1 - 2/(exp(2a)+1) -> out = base[o] - 2 * sum pc*r
//
// R4: R2/R3 counters showed VALUBusy ~34% => ~66% stall. LDS-pipe theory
// refuted (broadcast reads dedup; R3's LDS cut regressed). New theory:
// dependent-chain latency (fma->exp2->add->rcp->...->rcp, ~100+cyc) with
// too few interleaved chains (VGPR=64). Fix: manual 2-chain body (i and
// i+32, separate accumulators) + unroll 4 => 8 independent chains in
// flight. Structure otherwise identical to R2 (BT=16, 33KB LDS, 4 blk/CU).

#define GATE_C 14.426950408889634f   // 10*log2(e)
#define TANH_C 2.8853900817779268f   // 2*log2(e)

constexpr int B = 512, I = 128, O = 64, NB = 8, BT = 16;

__global__ __launch_bounds__(256, 4) void fe_main(
    const float* __restrict__ x, const float* __restrict__ k,
    const float* __restrict__ Ec, const float* __restrict__ Ps,
    const float* __restrict__ bias, const float* __restrict__ coef,
    float* __restrict__ out)
{
  __shared__ float4 p_lds[I * NB];        // {Ec, Ec*GATE_C, k*TANH_C, Ps*coef}, [i][n]
  __shared__ float2 xc_lds[BT][I + 1];    // {x, c}; +1 pad
  __shared__ float red[4];

  const int tid = threadIdx.x;
  const int o  = blockIdx.y;
  const int b0 = blockIdx.x * BT;

  // ---- stage packed params for this o, accumulate base[o] partial ----
  float pbase = 0.f;
  for (int e = tid; e < I * NB; e += 256) {
    const int i = e >> 3, n = e & 7;
    const int g = (i * O + o) * NB + n;
    const float ec = Ec[g], kk = k[g], ps = Ps[g], cf = coef[g], bs = bias[g];
    const float pc = ps * cf;
    p_lds[e] = make_float4(ec, ec * GATE_C, kk * TANH_C, pc);
    pbase += fmaf(bs, cf, pc);
  }

  // ---- stage {x, c} for this batch tile (coalesced) ----
  for (int e = tid; e < BT * I; e += 256) {
    const int bl = e >> 7, i = e & 127;
    const int bg = b0 + bl;
    const float xv = x[bg * I + i];
    const float pv = (bg == 0) ? 0.f : x[(bg - 1) * I + i];
    const float c = -0.4f * __builtin_amdgcn_rcpf(
        1.f + __builtin_amdgcn_exp2f(GATE_C * (xv - pv)));
    xc_lds[bl][i] = make_float2(xv, c);
  }

  // base[o]: full-wave butterfly, one partial per wave
  #pragma unroll
  for (int m = 1; m < 64; m <<= 1) pbase += __shfl_xor(pbase, m);
  if ((tid & 63) == 0) red[tid >> 6] = pbase;
  __syncthreads();

  // ---- main loop: thread = (bl, ih, n); two independent chains/iter ----
  const int bl = tid >> 4, ih = (tid >> 3) & 1, n = tid & 7;
  const int ibase = ih * 64;
  const float4* __restrict__ prow = p_lds + ibase * 8 + n;
  const float2* __restrict__ xrow = &xc_lds[bl][ibase];

  float accA = 0.f, accB = 0.f;
  #pragma unroll 4
  for (int it = 0; it < 32; ++it) {
    // chain A: i = ibase + it
    const float2 xcA = xrow[it];
    const float4 pA  = prow[it * 8];
    // chain B: i = ibase + it + 32
    const float2 xcB = xrow[it + 32];
    const float4 pB  = prow[(it + 32) * 8];

    const float eA = __builtin_amdgcn_exp2f(fmaf(xcA.x, GATE_C, pA.y));
    const float eB = __builtin_amdgcn_exp2f(fmaf(xcB.x, GATE_C, pB.y));
    const float sgA = __builtin_amdgcn_rcpf(1.f + eA);
    const float sgB = __builtin_amdgcn_rcpf(1.f + eB);
    const float bmA = fmaf(xcA.y, sgA, 1.f);
    const float bmB = fmaf(xcB.y, sgB, 1.f);
    const float inA = fmaf(pA.x, bmA, xcA.x);
    const float inB = fmaf(pB.x, bmB, xcB.x);
    const float tA = __builtin_amdgcn_exp2f(pA.z * inA);
    const float tB = __builtin_amdgcn_exp2f(pB.z * inB);
    const float rA = __builtin_amdgcn_rcpf(1.f + tA);
    const float rB = __builtin_amdgcn_rcpf(1.f + tB);
    accA = fmaf(pA.w, rA, accA);
    accB = fmaf(pB.w, rB, accB);
  }
  float acc = accA + accB;

  // reduce over n (dist 1,2,4) then ih (dist 8) — all within wave
  acc += __shfl_xor(acc, 1);
  acc += __shfl_xor(acc, 2);
  acc += __shfl_xor(acc, 4);
  acc += __shfl_xor(acc, 8);

  if ((tid & 15) == 0) {
    const float base = red[0] + red[1] + red[2] + red[3];
    out[(b0 + bl) * O + o] = fmaf(-2.f, acc, base);
  }
}

extern "C" void kernel_launch(void* const* d_in, const int* in_sizes, int n_in,
                              void* d_out, int out_size, void* d_ws, size_t ws_size,
                              hipStream_t stream) {
  const float* x    = (const float*)d_in[0];
  const float* k    = (const float*)d_in[1];
  const float* Ec   = (const float*)d_in[2];
  const float* Ps   = (const float*)d_in[3];
  const float* bias = (const float*)d_in[4];
  const float* coef = (const float*)d_in[5];
  float* out = (float*)d_out;

  dim3 grid(B / BT, O);   // 32 batch tiles x 64 output channels
  fe_main<<<grid, 256, 0, stream>>>(x, k, Ec, Ps, bias, coef, out);
}